// Round 3
// baseline (451.659 us; speedup 1.0000x reference)
//
#include <hip/hip_runtime.h>
#include <hip/hip_bf16.h>

#define NH 96          // heads
#define NE 1537        // edge table rows
#define ND 5           // multi-hop
#define NN 128         // nodes
#define NB 16          // batch
#define NP1 129        // N+1
#define OUT_PLANE (NP1 * NP1)   // 16641

__device__ __forceinline__ float bflo(unsigned u) { return __uint_as_float(u << 16); }
__device__ __forceinline__ float bfhi(unsigned u) { return __uint_as_float(u & 0xffff0000u); }

// ---------------------------------------------------------------------------
// Kernel 1: M[d][e][h] = sum_k edge_enc_w[e][k] * W[d][k][h], stored bf16 (RTNE)
// W[d][k][h] = edge_dis_w[(d*32+k)*96 + h].  Each thread computes 4 heads.
// ---------------------------------------------------------------------------
__global__ __launch_bounds__(256) void k_build_M(
    const float* __restrict__ E, const float* __restrict__ Wd,
    unsigned short* __restrict__ M) {
  int o = blockIdx.x * 256 + threadIdx.x;          // (d,e,h4)
  if (o >= ND * NE * (NH / 4)) return;
  int h4 = o % (NH / 4);
  int r  = o / (NH / 4);
  int e  = r % NE;
  int d  = r / NE;
  const float* __restrict__ Er = E + e * 32;
  const float4* __restrict__ Wp = (const float4*)(Wd + d * 32 * NH + h4 * 4);
  float4 acc = {0.f, 0.f, 0.f, 0.f};
#pragma unroll 8
  for (int k = 0; k < 32; ++k) {
    float ev = Er[k];
    float4 w = Wp[k * (NH / 4)];
    acc.x = fmaf(ev, w.x, acc.x);
    acc.y = fmaf(ev, w.y, acc.y);
    acc.z = fmaf(ev, w.z, acc.z);
    acc.w = fmaf(ev, w.w, acc.w);
  }
  const float av[4] = {acc.x, acc.y, acc.z, acc.w};
  unsigned short* mp = M + (r * NH + h4 * 4);
#pragma unroll
  for (int c = 0; c < 4; ++c) {
    unsigned u = __float_as_uint(av[c]);
    unsigned rb = (u + 0x7fffu + ((u >> 16) & 1u)) >> 16;  // RTNE
    mp[c] = (unsigned short)rb;
  }
}

// ---------------------------------------------------------------------------
// Kernel 2: interior cells (i>=1, j>=1).
// Block = (b, i) row x 64-wide j tile. 512 threads = 64 pairs x 8 head-groups
// of 12 heads. Spatial bias + hop-scale deferred to phase 2 (register relief).
// Normal stores (NO nontemporal: NT caused 5.6x write amplification in R2).
// ---------------------------------------------------------------------------
__global__ __launch_bounds__(512, 8) void k_interior(
    const float* __restrict__ ab, const int* __restrict__ spos,
    const int* __restrict__ eidx, const float* __restrict__ spw,
    const unsigned short* __restrict__ M, float* __restrict__ out) {
  const int jt = blockIdx.x;   // 0..1
  const int n  = blockIdx.y;   // 0..127  (i-1)
  const int b  = blockIdx.z;   // 0..15
  const int i  = n + 1;
  const int j0 = jt * 64;

  __shared__ int   s_idx[960];       // 64 pairs x 15 edge indices
  __shared__ int   s_sp[64];
  __shared__ float s_eb[64][97];     // stride-97: conflict-free both phases

  const int tid = threadIdx.x;
  const int pairbase = (b * NN + n) * NN + j0;
  // stage 960 edge indices as 240 int4 (16B-aligned)
  if (tid < 240) {
    ((int4*)s_idx)[tid] = ((const int4*)(eidx + (long)pairbase * 15))[tid];
  }
  if (tid >= 256 && tid < 320) s_sp[tid - 256] = spos[pairbase + (tid - 256)];
  __syncthreads();

  const int p  = tid >> 3;     // pair within tile (0..63)
  const int q  = tid & 7;      // head group
  const int hq = q * 12;       // 12 heads = 24 B of bf16 (8B-aligned)

  float acc[12];
#pragma unroll
  for (int c = 0; c < 12; ++c) acc[c] = 0.f;

  const int* mi = s_idx + p * 15;
#pragma unroll
  for (int g = 0; g < 15; ++g) {
    const int d = g / 3;                       // constant after unroll
    const int e = mi[g];
    const uint2* __restrict__ r = (const uint2*)(M + (d * NE + e) * NH + hq);
    uint2 w0 = r[0], w1 = r[1], w2 = r[2];
    acc[0]  += bflo(w0.x); acc[1]  += bfhi(w0.x);
    acc[2]  += bflo(w0.y); acc[3]  += bfhi(w0.y);
    acc[4]  += bflo(w1.x); acc[5]  += bfhi(w1.x);
    acc[6]  += bflo(w1.y); acc[7]  += bfhi(w1.y);
    acc[8]  += bflo(w2.x); acc[9]  += bfhi(w2.x);
    acc[10] += bflo(w2.y); acc[11] += bfhi(w2.y);
  }

#pragma unroll
  for (int c = 0; c < 12; ++c) s_eb[p][hq + c] = acc[c];
  __syncthreads();

  // phase 2: lanes along j -> coalesced 256B write segments; h uniform per group
  const int jl = tid & 63;
  const int hb = tid >> 6;     // 0..7, 12 heads each
  const int spn = s_sp[jl];
  const int spc = min(max(spn - 1, 1), 5);
  const float scale = 1.0f / (3.0f * (float)spc);
  const float a2v = 2.0f * ab[(b * NP1 + i) * NP1 + 1 + j0 + jl];
  const int obase = i * NP1 + 1 + j0 + jl;

  // spatial bias row gather: 48B chunk, 16B-aligned (spn*384 + hb*48)
  const float4* __restrict__ sr = (const float4*)(spw + spn * NH + hb * 12);
  float4 s0 = sr[0], s1 = sr[1], s2 = sr[2];
  float sv[12] = {s0.x, s0.y, s0.z, s0.w, s1.x, s1.y, s1.z, s1.w,
                  s2.x, s2.y, s2.z, s2.w};

#pragma unroll
  for (int c = 0; c < 12; ++c) {
    const int h = hb * 12 + c;
    const float v = s_eb[jl][h] * scale + sv[c] + a2v;
    out[((h >> 3) * 128 + b * 8 + (h & 7)) * OUT_PLANE + obase] = v;
  }
}

// ---------------------------------------------------------------------------
// Kernel 3: boundary cells: row i=0 (all j) and column j=0 (i>=1):
//   out = 2*attn_bias + virt_w[h]
// ---------------------------------------------------------------------------
__global__ __launch_bounds__(256) void k_boundary(
    const float* __restrict__ ab, const float* __restrict__ virt,
    float* __restrict__ out) {
  const int bh = blockIdx.x;   // 0..1535 = b*96+h
  const int b = bh / NH;
  const int h = bh % NH;
  const float t = virt[h];
  const int tid = threadIdx.x;
  const int base = ((h >> 3) * 128 + b * 8 + (h & 7)) * OUT_PLANE;
  if (tid < NP1) {
    out[base + tid] = 2.f * ab[(b * NP1) * NP1 + tid] + t;
  }
  if (tid < NN) {
    const int i = tid + 1;     // 1..128
    out[base + i * NP1] = 2.f * ab[(b * NP1 + i) * NP1] + t;
  }
}

// ---------------------------------------------------------------------------
extern "C" void kernel_launch(void* const* d_in, const int* in_sizes, int n_in,
                              void* d_out, int out_size, void* d_ws, size_t ws_size,
                              hipStream_t stream) {
  const float* ab   = (const float*)d_in[0];   // attn_bias     [16,129,129] f32
  const int*   spos = (const int*)d_in[1];     // spatial_pos   [16,128,128] i32
  // d_in[2] node_attr: unused by reference math
  const int*   eidx = (const int*)d_in[3];     // edge_input    [16,128,128,5,3] i32
  const float* eenc = (const float*)d_in[4];   // edge_enc_w    [1537,32] f32
  const float* edis = (const float*)d_in[5];   // edge_dis_w    [393216,1] f32
  const float* spw  = (const float*)d_in[6];   // spatial_enc_w [522,96] f32
  const float* virt = (const float*)d_in[7];   // virt_w        [1,96] f32
  float* out = (float*)d_out;

  unsigned short* M = (unsigned short*)d_ws;   // 5*1537*96 bf16 = 1.48 MB

  const int totM = ND * NE * (NH / 4);
  k_build_M<<<(totM + 255) / 256, 256, 0, stream>>>(eenc, edis, M);
  k_interior<<<dim3(2, NN, NB), 512, 0, stream>>>(ab, spos, eidx, spw, M, out);
  k_boundary<<<NB * NH, 256, 0, stream>>>(ab, virt, out);
}

// Round 6
// 213.829 us; speedup vs baseline: 2.1122x; 2.1122x over previous
//
#include <hip/hip_runtime.h>
#include <hip/hip_bf16.h>

#define NH 96          // heads
#define NE 1537        // edge table rows
#define ND 5           // multi-hop
#define NN 128         // nodes
#define NB 16          // batch
#define NP1 129        // N+1
#define OUT_PLANE (NP1 * NP1)   // 16641

__device__ __forceinline__ float bflo(unsigned u) { return __uint_as_float(u << 16); }
__device__ __forceinline__ float bfhi(unsigned u) { return __uint_as_float(u & 0xffff0000u); }

// ---------------------------------------------------------------------------
// Kernel 1: M2[(d*NE+e)*2+half][64 shorts] (48 head values bf16 + 16 pad):
// 128B-aligned rows so one half-row = exactly one cache line.
// M[d][e][h] = sum_k edge_enc_w[e][k] * W[d][k][h], W[d][k][h]=edge_dis_w[(d*32+k)*96+h]
// ---------------------------------------------------------------------------
__global__ __launch_bounds__(256) void k_build_M(
    const float* __restrict__ E, const float* __restrict__ Wd,
    unsigned short* __restrict__ M) {
  int o = blockIdx.x * 256 + threadIdx.x;          // (d,e,h4): h4 = 4-head group
  if (o >= ND * NE * 24) return;
  int h4 = o % 24;
  int r  = o / 24;                                 // d*NE+e
  int e  = r % NE;
  int d  = r / NE;
  const float* __restrict__ Er = E + e * 32;
  const float4* __restrict__ Wp = (const float4*)(Wd + d * 32 * NH + h4 * 4);
  float4 acc = {0.f, 0.f, 0.f, 0.f};
#pragma unroll 8
  for (int k = 0; k < 32; ++k) {
    float ev = Er[k];
    float4 w = Wp[k * 24];
    acc.x = fmaf(ev, w.x, acc.x);
    acc.y = fmaf(ev, w.y, acc.y);
    acc.z = fmaf(ev, w.z, acc.z);
    acc.w = fmaf(ev, w.w, acc.w);
  }
  const float av[4] = {acc.x, acc.y, acc.z, acc.w};
  unsigned rb[4];
#pragma unroll
  for (int c = 0; c < 4; ++c) {
    unsigned u = __float_as_uint(av[c]);
    rb[c] = (u + 0x7fffu + ((u >> 16) & 1u)) >> 16;   // RTNE to bf16
  }
  const int half = (h4 >= 12);
  unsigned short* mp = M + (size_t)(r * 2 + half) * 64 + (h4 - half * 12) * 4;
  uint2 pk;
  pk.x = rb[0] | (rb[1] << 16);
  pk.y = rb[2] | (rb[3] << 16);
  *(uint2*)mp = pk;   // 8B-aligned
}

// ---------------------------------------------------------------------------
// Kernel 2: interior cells (i>=1, j>=1), split by head-half.
// Block = (b, i, jt 32-wide j tile, head-half of 48). 256 threads = 32 pairs
// x 8 lanes; lanes q=0..5 fetch the pair's 96B half-row with ONE dwordx4
// (1 cache line). LDS padded to ~36KB to cap residency at 4 blocks/CU
// (keeps M-table + write streams inside the 4MB/XCD L2 — R2/R3 thrash fix).
// ---------------------------------------------------------------------------
__global__ __launch_bounds__(256, 4) void k_interior(
    const float* __restrict__ ab, const int* __restrict__ spos,
    const int* __restrict__ eidx, const float* __restrict__ spw,
    const unsigned short* __restrict__ M, float* __restrict__ out) {
  const int half = blockIdx.x & 1;     // head half: h in [half*48, half*48+48)
  const int jt   = blockIdx.x >> 1;    // 0..3
  const int n  = blockIdx.y;           // 0..127  (i-1)
  const int b  = blockIdx.z;           // 0..15
  const int i  = n + 1;
  const int j0 = jt * 32;

  __shared__ int   s_idx[480];       // 32 pairs x 15 edge indices
  __shared__ int   s_sp[32];
  __shared__ float s_eb[32][49];     // stride-49 (odd): conflict-free
  __shared__ float s_pad[7000];      // occupancy limiter: total LDS ~= 36.3 KB

  const int tid = threadIdx.x;
  if (tid == 0) { volatile float* vp = s_pad; vp[0] = 0.f; }  // keep s_pad

  const int pairbase = (b * NN + n) * NN + j0;   // multiple of 32
  if (tid < 120) {
    ((int4*)s_idx)[tid] = ((const int4*)(eidx + (size_t)pairbase * 15))[tid];
  }
  if (tid >= 128 && tid < 160) s_sp[tid - 128] = spos[pairbase + (tid - 128)];
  __syncthreads();

  const int p = tid >> 3;     // pair within tile (0..31)
  const int q = tid & 7;      // lane within pair; q<6 active in gather

  if (q < 6) {
    float acc[8];
#pragma unroll
    for (int c = 0; c < 8; ++c) acc[c] = 0.f;

    const int* mi = s_idx + p * 15;
#pragma unroll
    for (int g = 0; g < 15; ++g) {
      const int d = g / 3;                       // constant after unroll
      const int e = mi[g];
      // half-row base is 128B-aligned; q*16B chunk: whole row = 1 line
      const uint4 w = *(const uint4*)(M + ((size_t)((d * NE + e) * 2 + half)) * 64 + q * 8);
      acc[0] += bflo(w.x); acc[1] += bfhi(w.x);
      acc[2] += bflo(w.y); acc[3] += bfhi(w.y);
      acc[4] += bflo(w.z); acc[5] += bfhi(w.z);
      acc[6] += bflo(w.w); acc[7] += bfhi(w.w);
    }

    // hop normalizer + spatial bias (pair-major: 8 rows per inst, float4-aligned)
    const int spn = s_sp[p];
    const int spc = min(max(spn - 1, 1), 5);
    const float scale = 1.0f / (3.0f * (float)spc);
    const float4* __restrict__ sr = (const float4*)(spw + spn * NH + half * 48 + q * 8);
    float4 s0 = sr[0], s1 = sr[1];
    const float sv[8] = {s0.x, s0.y, s0.z, s0.w, s1.x, s1.y, s1.z, s1.w};
#pragma unroll
    for (int c = 0; c < 8; ++c) s_eb[p][q * 8 + c] = acc[c] * scale + sv[c];
  }
  __syncthreads();

  // phase B: lanes along j -> coalesced 128B write segments; attn_bias added here
  const int jl = tid & 31;
  const int hb = tid >> 5;     // 0..7, 6 planes each
  const float a2v = 2.0f * ab[(b * NP1 + i) * NP1 + 1 + j0 + jl];
  const int obase = i * NP1 + 1 + j0 + jl;
#pragma unroll
  for (int c = 0; c < 6; ++c) {
    const int hl = hb * 6 + c;           // 0..47
    const int h  = half * 48 + hl;
    out[((h >> 3) * 128 + b * 8 + (h & 7)) * OUT_PLANE + obase] = s_eb[jl][hl] + a2v;
  }
}

// ---------------------------------------------------------------------------
// Kernel 3: boundary cells: row i=0 (all j) and column j=0 (i>=1):
//   out = 2*attn_bias + virt_w[h]
// ---------------------------------------------------------------------------
__global__ __launch_bounds__(256) void k_boundary(
    const float* __restrict__ ab, const float* __restrict__ virt,
    float* __restrict__ out) {
  const int bh = blockIdx.x;   // 0..1535 = b*96+h
  const int b = bh / NH;
  const int h = bh % NH;
  const float t = virt[h];
  const int tid = threadIdx.x;
  const int base = ((h >> 3) * 128 + b * 8 + (h & 7)) * OUT_PLANE;
  if (tid < NP1) {
    out[base + tid] = 2.f * ab[(b * NP1) * NP1 + tid] + t;
  }
  if (tid < NN) {
    const int i = tid + 1;     // 1..128
    out[base + i * NP1] = 2.f * ab[(b * NP1 + i) * NP1] + t;
  }
}

// ---------------------------------------------------------------------------
extern "C" void kernel_launch(void* const* d_in, const int* in_sizes, int n_in,
                              void* d_out, int out_size, void* d_ws, size_t ws_size,
                              hipStream_t stream) {
  const float* ab   = (const float*)d_in[0];   // attn_bias     [16,129,129] f32
  const int*   spos = (const int*)d_in[1];     // spatial_pos   [16,128,128] i32
  // d_in[2] node_attr: unused by reference math
  const int*   eidx = (const int*)d_in[3];     // edge_input    [16,128,128,5,3] i32
  const float* eenc = (const float*)d_in[4];   // edge_enc_w    [1537,32] f32
  const float* edis = (const float*)d_in[5];   // edge_dis_w    [393216,1] f32
  const float* spw  = (const float*)d_in[6];   // spatial_enc_w [522,96] f32
  const float* virt = (const float*)d_in[7];   // virt_w        [1,96] f32
  float* out = (float*)d_out;

  unsigned short* M = (unsigned short*)d_ws;   // 5*1537*2 rows x 128B = 1.97 MB

  const int totM = ND * NE * 24;
  k_build_M<<<(totM + 255) / 256, 256, 0, stream>>>(eenc, edis, M);
  k_interior<<<dim3(8, NN, NB), 256, 0, stream>>>(ab, spos, eidx, spw, M, out);
  k_boundary<<<NB * NH, 256, 0, stream>>>(ab, virt, out);
}